// Round 9
// baseline (441.076 us; speedup 1.0000x reference)
//
#include <hip/hip_runtime.h>
#include <hip/hip_bf16.h>
#include <stdint.h>

// MoE: B=4,S=2048,D=1024,E=8,TOPK=2,I=938. Sparse top-2 routing + bf16 MFMA GEMMs.
// R15 = R10 GEMM cores (verified 407.8us: 128x256/BK=32/3-slot, 2 blocks/CU)
//       + dataflow cuts:
//   (1) combine fused away: gemm2_shared plain-writes ALL of Out (stream-ordered
//       first), gemm2_routed fp32-atomicAdds routed contributions (skip pad rows).
//       Removes combine kernel (~100MB), Yr buffer (+34MB writes), slotOf.
//       Idempotent across graph replays (shared overwrites before routed adds).
//   (2) gemm2 K=960 (NTK=30): A-cols 938..1023 are exact zeros; skip 2 K-tiles.

typedef __bf16 bf16_t;
typedef __bf16 bf16x8 __attribute__((ext_vector_type(8)));
typedef float  f32x4  __attribute__((ext_vector_type(4)));

#define TOKENS    8192
#define DMODEL    1024
#define NEXP      8
#define INTER     938
#define AP        1024     // padded inter dim (A cols / gemm2 K / Wd cols)
#define GUP       2048     // padded gate(1024)+up(1024) rows per expert
#define CAP_ROWS  17408    // 16384 + 8*128
#define MAX_TILES 144
#define SH_TILES  64       // 8192/128 shared M-tiles
#define BK        32
#define SLOT      12288    // LDS slot elements (24KB): A[128x32]=4096 | B[256x32]=8192

#define G1SLOTS   2048     // 8 residues x 256 ranks
#define G1PER     256
#define G2SLOTS   1024     // 8 residues x 128 ranks (routed only now)
#define G2PER     128

#define PLAN_BLOCKS 16
#define TOK_PER_PLAN (TOKENS / PLAN_BLOCKS)

// ---- async global->LDS, 16B per lane; LDS dest = wave-uniform base + lane*16 ----
__device__ __forceinline__ void async16(const bf16_t* g, bf16_t* l) {
  __builtin_amdgcn_global_load_lds(
      (__attribute__((address_space(1))) void*)(g),
      (__attribute__((address_space(3))) void*)(l),
      16, 0, 0);
}

__device__ __forceinline__ unsigned short f2bu(float f) {
  bf16_t b = (bf16_t)f;
  unsigned short u;
  __builtin_memcpy(&u, &b, 2);
  return u;
}

// ---------------- weight re-layout converts ----------------
__global__ void conv_gu_pad(const float4* __restrict__ src, ushort4* __restrict__ dst) {
  int i = blockIdx.x * 256 + threadIdx.x;
  int e = i >> 19;            // GUP*256 = 2^19
  int rem = i & 524287;
  int r = rem >> 8;
  int c4 = rem & 255;
  const float4* s = src + (size_t)e * (1876 * 256);
  float4 v = {0.f, 0.f, 0.f, 0.f};
  if (r < INTER) v = s[r * 256 + c4];
  else if (r >= 1024 && r < 1024 + INTER) v = s[(r - 86) * 256 + c4];
  ushort4 o;
  o.x = f2bu(v.x); o.y = f2bu(v.y); o.z = f2bu(v.z); o.w = f2bu(v.w);
  dst[i] = o;
}

__global__ void conv_dn_pad(const float* __restrict__ src, bf16_t* __restrict__ dst) {
  int i = blockIdx.x * 256 + threadIdx.x;
  int e = i >> 20;
  int rem = i & 1048575;
  int n = rem >> 10;
  int c = rem & 1023;
  float v = (c < INTER) ? src[(size_t)e * (1024 * INTER) + n * INTER + c] : 0.f;
  dst[i] = (bf16_t)v;
}

// ---------------- routing ----------------
__global__ void init_kernel(int* __restrict__ row_token) {
  int i = blockIdx.x * 256 + threadIdx.x;
  if (i < CAP_ROWS) row_token[i] = -1;
}

__global__ __launch_bounds__(256) void router_kernel(
    const float4* __restrict__ X4, const float4* __restrict__ GW4,
    bf16_t* __restrict__ Xb, int* __restrict__ e01, float* __restrict__ w01) {
  int token = blockIdx.x * 4 + (threadIdx.x >> 6);
  int lane = threadIdx.x & 63;
  const float4* x4 = X4 + (size_t)token * 256;

  float4 xv[4];
#pragma unroll
  for (int j = 0; j < 4; j++) xv[j] = x4[lane + 64 * j];

  ushort4* xbrow = (ushort4*)(Xb + (size_t)token * DMODEL);
#pragma unroll
  for (int j = 0; j < 4; j++) {
    ushort4 r;
    r.x = f2bu(xv[j].x); r.y = f2bu(xv[j].y);
    r.z = f2bu(xv[j].z); r.w = f2bu(xv[j].w);
    xbrow[lane + 64 * j] = r;
  }

  float acc[NEXP];
#pragma unroll
  for (int e = 0; e < NEXP; e++) {
    float a = 0.f;
#pragma unroll
    for (int j = 0; j < 4; j++) {
      float4 g = GW4[e * 256 + lane + 64 * j];
      a += xv[j].x * g.x + xv[j].y * g.y + xv[j].z * g.z + xv[j].w * g.w;
    }
    acc[e] = a;
  }
#pragma unroll
  for (int off = 32; off > 0; off >>= 1)
#pragma unroll
    for (int e = 0; e < NEXP; e++) acc[e] += __shfl_down(acc[e], off, 64);

  if (lane == 0) {
    float mx = acc[0];
#pragma unroll
    for (int e = 1; e < NEXP; e++) mx = fmaxf(mx, acc[e]);
    float p[NEXP]; float s = 0.f;
#pragma unroll
    for (int e = 0; e < NEXP; e++) { p[e] = expf(acc[e] - mx); s += p[e]; }
    int i0 = 0;
#pragma unroll
    for (int e = 1; e < NEXP; e++) if (p[e] > p[i0]) i0 = e;
    int i1 = (i0 == 0) ? 1 : 0;
#pragma unroll
    for (int e = 0; e < NEXP; e++) if (e != i1 && e != i0 && p[e] > p[i1]) i1 = e;
    float p0 = p[i0] / s, p1 = p[i1] / s;
    float inv = 1.f / (p0 + p1 + 1e-8f);
    e01[token * 2 + 0] = i0; e01[token * 2 + 1] = i1;
    w01[token * 2 + 0] = p0 * inv; w01[token * 2 + 1] = p1 * inv;
  }
}

__global__ void hist_kernel(const int* __restrict__ e01, int* __restrict__ blockCounts) {
  __shared__ int h[NEXP];
  int t = threadIdx.x;
  if (t < NEXP) h[t] = 0;
  __syncthreads();
  int base = blockIdx.x * TOK_PER_PLAN * 2;
  for (int i = t; i < TOK_PER_PLAN * 2; i += 256) atomicAdd(&h[e01[base + i]], 1);
  __syncthreads();
  if (t < NEXP) blockCounts[blockIdx.x * NEXP + t] = h[t];
}

// ---------------- plan: blockBase, tileExpert, XCD-affine work lists ----------------
// 128-row tiles. gemm1: 8 f-blocks per mt (shared + routed, work-list).
// gemm2 work list: ROUTED ONLY (4 f-blocks of 256 out cols per routed mt).
__global__ __launch_bounds__(256) void plan_kernel(
    const int* __restrict__ blockCounts, int* __restrict__ blockBase,
    int* __restrict__ tileExpert, int* __restrict__ work1, int* __restrict__ work2) {
  __shared__ int cnt[8], tc[8], tb[8], n1[8], n2[8];
  __shared__ int f1n, f2n, f1c, f2c;
  __shared__ short free1[G1SLOTS];
  __shared__ short free2[G2SLOTS];
  const int t = threadIdx.x;

  if (t < 8) {
    int s = 0;
    for (int b = 0; b < PLAN_BLOCKS; b++) s += blockCounts[b * 8 + t];
    cnt[t] = s;
  }
  if (t == 0) { f1n = 0; f2n = 0; f1c = 0; f2c = 0; }
  __syncthreads();
  if (t == 0) {
    int o = 0;
    for (int e = 0; e < 8; e++) {
      tb[e] = o;
      tc[e] = (cnt[e] + 127) / 128;
      o += tc[e];
    }
    for (int s = 0; s < 8; s++) { n1[s] = 64 + 8 * tc[s]; n2[s] = 4 * tc[s]; }
  }
  __syncthreads();
  const int nT = tb[7] + tc[7];

  if (t < 8) {            // blockBase for scatter (rows)
    int run = tb[t] * 128;
    for (int b = 0; b < PLAN_BLOCKS; b++) {
      blockBase[b * 8 + t] = run;
      run += blockCounts[b * 8 + t];
    }
  }
  for (int i = t; i < MAX_TILES; i += 256) {   // tileExpert (128-row routed tiles)
    int e = 0;
#pragma unroll
    for (int x = 1; x < 8; x++) if (i >= tb[x]) e = x;
    tileExpert[i] = e;
  }
  for (int i = t; i < G1SLOTS; i += 256) work1[i] = -1;
  for (int i = t; i < G2SLOTS; i += 256) work2[i] = -1;
  __syncthreads();

  // own-rank fills. gemm1 shared: mt 0..63, f 0..7 -> residue mt&7, rank (mt>>3)*8+f
  for (int i = t; i < 512; i += 256) {
    int mt = i >> 3, f = i & 7;
    work1[(mt & 7) + 8 * ((mt >> 3) * 8 + f)] = (mt << 4) | f;
  }
  for (int i = t; i < 8 * nT; i += 256) {      // gemm1 routed: residue = expert
    int tt = i >> 3, f = i & 7;
    int e = 0;
#pragma unroll
    for (int x = 1; x < 8; x++) if (tt >= tb[x]) e = x;
    int rk = 64 + (tt - tb[e]) * 8 + f;
    if (rk < G1PER) work1[e + 8 * rk] = ((SH_TILES + tt) << 4) | f;
  }
  for (int i = t; i < 4 * nT; i += 256) {      // gemm2 routed
    int tt = i >> 2, f = i & 3;
    int e = 0;
#pragma unroll
    for (int x = 1; x < 8; x++) if (tt >= tb[x]) e = x;
    int rk = (tt - tb[e]) * 4 + f;
    if (rk < G2PER) work2[e + 8 * rk] = ((SH_TILES + tt) << 4) | f;
  }
  __syncthreads();

  // free slots (residues whose own list is short)
  for (int i = t; i < G1SLOTS; i += 256)
    if ((i >> 3) >= n1[i & 7]) free1[atomicAdd(&f1n, 1)] = (short)i;
  for (int i = t; i < G2SLOTS; i += 256)
    if ((i >> 3) >= n2[i & 7]) free2[atomicAdd(&f2n, 1)] = (short)i;
  __syncthreads();

  // overflow items (imbalanced experts) -> spill into free slots
  for (int i = t; i < 8 * nT; i += 256) {
    int tt = i >> 3, f = i & 7;
    int e = 0;
#pragma unroll
    for (int x = 1; x < 8; x++) if (tt >= tb[x]) e = x;
    int rk = 64 + (tt - tb[e]) * 8 + f;
    if (rk >= G1PER) work1[free1[atomicAdd(&f1c, 1)]] = ((SH_TILES + tt) << 4) | f;
  }
  for (int i = t; i < 4 * nT; i += 256) {
    int tt = i >> 2, f = i & 3;
    int e = 0;
#pragma unroll
    for (int x = 1; x < 8; x++) if (tt >= tb[x]) e = x;
    int rk = (tt - tb[e]) * 4 + f;
    if (rk >= G2PER) work2[free2[atomicAdd(&f2c, 1)]] = ((SH_TILES + tt) << 4) | f;
  }
}

// block-local ranks via LDS atomics (no slotOf needed: combine is fused away)
__global__ void scatter_kernel(const int* __restrict__ e01, const float* __restrict__ w01,
                               const int* __restrict__ blockBase,
                               int* __restrict__ row_token, float* __restrict__ row_weight) {
  __shared__ int cur[NEXP];
  __shared__ int base[NEXP];
  int t = threadIdx.x;
  if (t < NEXP) { cur[t] = 0; base[t] = blockBase[blockIdx.x * NEXP + t]; }
  __syncthreads();
  int tb = blockIdx.x * TOK_PER_PLAN;
  for (int i = t; i < TOK_PER_PLAN * 2; i += 256) {
    int e = e01[tb * 2 + i];
    int rank = atomicAdd(&cur[e], 1);
    int pos = base[e] + rank;
    row_token[pos] = tb + (i >> 1);
    row_weight[pos] = w01[tb * 2 + i];
  }
}

// ================= 128x256 / BK=32 / 3-slot GEMM core (R10, verified) =================
// 512 thr = 8 waves (2M x 4N): wave-tile 64x64, acc[4][4]. LDS slot 24KB
// (A 128x32 | B 256x32), 3 slots = 72KB -> 2 blocks/CU at VGPR<=128.
// Per K-tile t (read slot t%3, stage t+2 -> slot (t+2)%3):
//   {3 gloads for t+2 -> 8 ds_read -> setprio(1) 16 MFMA setprio(0) ->
//    vmcnt(3) [forces t+1's 3 loads, issued during t-1] -> barrier}
// One barrier per K-tile. Swizzle: 16B chunk c stored at c ^ ((row+(row>>2))&3).

#define KLOOP_BODY(STAGE3, NTK)                                                 \
  f32x4 acc[4][4];                                                              \
  _Pragma("unroll") for (int mi = 0; mi < 4; ++mi)                              \
  _Pragma("unroll") for (int ni = 0; ni < 4; ++ni)                              \
    acc[mi][ni] = (f32x4){0.f, 0.f, 0.f, 0.f};                                  \
  /* prologue: stage tiles 0,1 */                                               \
  STAGE3(0);                                                                    \
  apA += BK; bp0 += BK; bp1 += BK;                                              \
  STAGE3(SLOT);                                                                 \
  apA += BK; bp0 += BK; bp1 += BK;                                              \
  asm volatile("s_waitcnt vmcnt(3)" ::: "memory");                              \
  __builtin_amdgcn_s_barrier();                                                 \
  int sOff = 0, dOff = 2 * SLOT;                                                \
  _Pragma("unroll 1")                                                           \
  for (int t = 0; t < (NTK); ++t) {                                             \
    if (t < (NTK) - 2) {                                                        \
      STAGE3(dOff);                                                             \
      apA += BK; bp0 += BK; bp1 += BK;                                          \
    }                                                                           \
    bf16x8 av[4], bv[4];                                                        \
    const int aB = sOff + aBaseC, bB = sOff + bBaseC;                           \
    _Pragma("unroll") for (int mi = 0; mi < 4; ++mi)                            \
      av[mi] = *(const bf16x8*)&lds[aB + mi * 512];                             \
    _Pragma("unroll") for (int ni = 0; ni < 4; ++ni)                            \
      bv[ni] = *(const bf16x8*)&lds[bB + ni * 512];                             \
    __builtin_amdgcn_s_setprio(1);                                              \
    _Pragma("unroll") for (int mi = 0; mi < 4; ++mi)                            \
    _Pragma("unroll") for (int ni = 0; ni < 4; ++ni)                            \
      acc[mi][ni] = __builtin_amdgcn_mfma_f32_16x16x32_bf16(                    \
          av[mi], bv[ni], acc[mi][ni], 0, 0, 0);                                \
    __builtin_amdgcn_s_setprio(0);                                              \
    if (t < (NTK) - 2) {                                                        \
      asm volatile("s_waitcnt vmcnt(3)" ::: "memory");                          \
      __builtin_amdgcn_s_barrier();                                             \
    } else if (t == (NTK) - 2) {                                                \
      asm volatile("s_waitcnt vmcnt(0)" ::: "memory");                          \
      __builtin_amdgcn_s_barrier();                                             \
    }                                                                           \
    sOff += SLOT; if (sOff == 3 * SLOT) sOff = 0;                               \
    dOff += SLOT; if (dOff == 3 * SLOT) dOff = 0;                               \
  }

// ---------------- GEMM1 (fused shared+routed): A[M,1024] = swiglu(X @ Wgu^T) ----------------
// item = (mt<<4)|f0, f0 0..7. N-tile 256 = 128 gate + 128 up interleaved at 16-col
// granularity; inter cols f0*128..f0*128+127. Writes all 1024 padded A cols
// (pad cols exact 0 from zero weights).
__global__ __launch_bounds__(512, 4) void gemm1_fused(
    const bf16_t* __restrict__ Xb, const bf16_t* __restrict__ WS,
    const bf16_t* __restrict__ WE, bf16_t* __restrict__ As, bf16_t* __restrict__ Ar,
    const int* __restrict__ row_token, const int* __restrict__ tileExpert,
    const int* __restrict__ work1) {
  const int item = work1[blockIdx.x];
  if (item < 0) return;
  const int mt = item >> 4;
  const int f0 = item & 15;

  const bf16_t* W; bf16_t* Aout; int m0; const int* rtok = nullptr;
  if (mt < SH_TILES) {
    m0 = mt * 128; W = WS; Aout = As;
  } else {
    int rt = mt - SH_TILES;
    m0 = rt * 128; W = WE + (size_t)tileExpert[rt] * (GUP * DMODEL);
    Aout = Ar; rtok = row_token;
  }

  __shared__ bf16_t lds[3 * SLOT];   // 72KB

  const int tid = threadIdx.x;
  const int w = tid >> 6, lane = tid & 63;
  const int wm = w >> 2, wn = w & 3;
  const int lr = lane & 15, quad = lane >> 4;

  // staging sources: lane -> (row = w*16 + lane>>2, chunk = (lane&3) ^ swz(row))
  const int arow = w * 16 + (lane >> 2);
  const int srcch = ((lane & 3) ^ (((lane >> 2) + (lane >> 4)) & 3)) * 8;
  int tokA = m0 + arow;
  if (rtok) { int tt = rtok[tokA]; tokA = (tt < 0) ? 0 : tt; }
  const bf16_t* apA = Xb + (size_t)tokA * DMODEL + srcch;
  const bf16_t* bp0; const bf16_t* bp1;
  {
    int n = arow;                         // B gload 0: n rows 0..127
    int ni = n >> 4;
    int wr = (ni & 1) * 1024 + f0 * 128 + (ni >> 1) * 16 + (n & 15);
    bp0 = W + (size_t)wr * DMODEL + srcch;
    n = 128 + arow;                       // B gload 1: n rows 128..255
    ni = n >> 4;
    wr = (ni & 1) * 1024 + f0 * 128 + (ni >> 1) * 16 + (n & 15);
    bp1 = W + (size_t)wr * DMODEL + srcch;
  }

  // fragment read bases (chunk term invariant across mi/ni: strides = 0 mod 4)
  const int chA = (quad ^ ((lr + (lr >> 2)) & 3)) * 8;
  const int aBaseC = (wm * 64 + lr) * 32 + chA;
  const int bBaseC = 4096 + (wn * 64 + lr) * 32 + chA;

#define STAGE3_G1(D)                                                            \
  do {                                                                          \
    async16(apA, &lds[(D) + w * 512]);                                          \
    async16(bp0, &lds[(D) + 4096 + w * 512]);                                   \
    async16(bp1, &lds[(D) + 8192 + w * 512]);                                   \
  } while (0)

  KLOOP_BODY(STAGE3_G1, 32)

  // epilogue: gate = acc[mi][2j], up = acc[mi][2j+1]; col = f0*128 + (wn*2+j)*16 + lr
#pragma unroll
  for (int mi = 0; mi < 4; mi++)
#pragma unroll
    for (int j = 0; j < 2; j++)
#pragma unroll
      for (int r = 0; r < 4; r++) {
        int row = m0 + wm * 64 + mi * 16 + quad * 4 + r;
        int col = f0 * 128 + (wn * 2 + j) * 16 + lr;
        float g = acc[mi][2 * j][r], u = acc[mi][2 * j + 1][r];
        float v = (g / (1.f + __expf(-g))) * u;
        Aout[(size_t)row * AP + col] = (bf16_t)v;
      }
}

// ---------------- GEMM2 shared: Out[M,1024] = As @ WdS^T, K=960, plain write ----------------
// Covers EVERY Out element exactly once (must run before gemm2_routed in-stream).
// grid = 256: mt = bid>>2 (0..63), n0 = (bid&3)*256.
#define STAGE3_G2(D)                                                            \
  do {                                                                          \
    async16(apA, &lds[(D) + w * 512]);                                          \
    async16(bp0, &lds[(D) + 4096 + w * 512]);                                   \
    async16(bp1, &lds[(D) + 8192 + w * 512]);                                   \
  } while (0)

__global__ __launch_bounds__(512, 4) void gemm2_shared(
    const bf16_t* __restrict__ As, const bf16_t* __restrict__ WS,
    float* __restrict__ Out) {
  const int mt = blockIdx.x >> 2;
  const int n0 = (blockIdx.x & 3) * 256;
  const int m0 = mt * 128;
  const bf16_t* A = As;
  const bf16_t* W = WS;

  __shared__ bf16_t lds[3 * SLOT];

  const int tid = threadIdx.x;
  const int w = tid >> 6, lane = tid & 63;
  const int wm = w >> 2, wn = w & 3;
  const int lr = lane & 15, quad = lane >> 4;

  const int arow = w * 16 + (lane >> 2);
  const int srcch = ((lane & 3) ^ (((lane >> 2) + (lane >> 4)) & 3)) * 8;
  const bf16_t* apA = A + (size_t)(m0 + arow) * AP + srcch;
  const bf16_t* bp0 = W + (size_t)(n0 + arow) * AP + srcch;
  const bf16_t* bp1 = W + (size_t)(n0 + 128 + arow) * AP + srcch;

  const int chA = (quad ^ ((lr + (lr >> 2)) & 3)) * 8;
  const int aBaseC = (wm * 64 + lr) * 32 + chA;
  const int bBaseC = 4096 + (wn * 64 + lr) * 32 + chA;

  KLOOP_BODY(STAGE3_G2, 30)

#pragma unroll
  for (int mi = 0; mi < 4; mi++) {
#pragma unroll
    for (int r = 0; r < 4; r++) {
      int row = m0 + wm * 64 + mi * 16 + quad * 4 + r;
#pragma unroll
      for (int ni = 0; ni < 4; ni++) {
        int col = n0 + wn * 64 + ni * 16 + lr;
        Out[(size_t)row * DMODEL + col] = acc[mi][ni][r];
      }
    }
  }
}

// ---------------- GEMM2 routed: Out[tok] += rw * (Ar @ WdE^T), K=960, atomicAdd ----------------
// item = ((SH_TILES+tt)<<4)|f, f 0..3, n0 = f*256. Padding rows (row_token<0) skipped.
__global__ __launch_bounds__(512, 4) void gemm2_routed(
    const bf16_t* __restrict__ Ar, const bf16_t* __restrict__ WE,
    float* __restrict__ Out,
    const int* __restrict__ row_token, const float* __restrict__ row_weight,
    const int* __restrict__ tileExpert, const int* __restrict__ work2) {
  const int item = work2[blockIdx.x];
  if (item < 0) return;
  const int rt = (item >> 4) - SH_TILES;
  const int n0 = (item & 15) * 256;
  const int m0 = rt * 128;
  const bf16_t* A = Ar;
  const bf16_t* W = WE + (size_t)tileExpert[rt] * (DMODEL * AP);

  __shared__ bf16_t lds[3 * SLOT];

  const int tid = threadIdx.x;
  const int w = tid >> 6, lane = tid & 63;
  const int wm = w >> 2, wn = w & 3;
  const int lr = lane & 15, quad = lane >> 4;

  const int arow = w * 16 + (lane >> 2);
  const int srcch = ((lane & 3) ^ (((lane >> 2) + (lane >> 4)) & 3)) * 8;
  const bf16_t* apA = A + (size_t)(m0 + arow) * AP + srcch;
  const bf16_t* bp0 = W + (size_t)(n0 + arow) * AP + srcch;
  const bf16_t* bp1 = W + (size_t)(n0 + 128 + arow) * AP + srcch;

  const int chA = (quad ^ ((lr + (lr >> 2)) & 3)) * 8;
  const int aBaseC = (wm * 64 + lr) * 32 + chA;
  const int bBaseC = 4096 + (wn * 64 + lr) * 32 + chA;

  KLOOP_BODY(STAGE3_G2, 30)

#pragma unroll
  for (int mi = 0; mi < 4; mi++) {
#pragma unroll
    for (int r = 0; r < 4; r++) {
      int row = m0 + wm * 64 + mi * 16 + quad * 4 + r;
      int tok = row_token[row];
      if (tok >= 0) {
        float rw = row_weight[row];
#pragma unroll
        for (int ni = 0; ni < 4; ni++) {
          int col = n0 + wn * 64 + ni * 16 + lr;
          atomicAdd(&Out[(size_t)tok * DMODEL + col], rw * acc[mi][ni][r]);
        }
      }
    }
  }
}

// ---------------- launch ----------------
extern "C" void kernel_launch(void* const* d_in, const int* in_sizes, int n_in,
                              void* d_out, int out_size, void* d_ws, size_t ws_size,
                              hipStream_t stream) {
  const float* X   = (const float*)d_in[0];
  const float* GW  = (const float*)d_in[1];
  const float* SGU = (const float*)d_in[2];
  const float* SD  = (const float*)d_in[3];
  const float* EGU = (const float*)d_in[4];
  const float* ED  = (const float*)d_in[5];
  float* Out = (float*)d_out;

  char* ws = (char*)d_ws;
  size_t o = 0;
  auto alloc = [&](size_t b) -> char* {
    char* p = ws + o;
    o = (o + b + 255) & ~(size_t)255;
    return p;
  };
  bf16_t* Xb    = (bf16_t*)alloc((size_t)TOKENS * DMODEL * 2);          // 16.8 MB
  bf16_t* WguSP = (bf16_t*)alloc((size_t)GUP * DMODEL * 2);             // 4.2 MB
  bf16_t* WdSP  = (bf16_t*)alloc((size_t)DMODEL * AP * 2);              // 2.1 MB
  bf16_t* WguEP = (bf16_t*)alloc((size_t)NEXP * GUP * DMODEL * 2);      // 33.6 MB
  bf16_t* WdEP  = (bf16_t*)alloc((size_t)NEXP * DMODEL * AP * 2);       // 16.8 MB
  bf16_t* As    = (bf16_t*)alloc((size_t)TOKENS * AP * 2);              // 16.8 MB
  bf16_t* Ar    = (bf16_t*)alloc((size_t)CAP_ROWS * AP * 2);            // 35.7 MB
  int*    e01    = (int*)alloc(TOKENS * 2 * 4);
  float*  w01    = (float*)alloc(TOKENS * 2 * 4);
  int*    blkCnt = (int*)alloc(PLAN_BLOCKS * NEXP * 4);
  int*    blkBas = (int*)alloc(PLAN_BLOCKS * NEXP * 4);
  int*    tileEx = (int*)alloc(MAX_TILES * 4);
  int*    work1  = (int*)alloc(G1SLOTS * 4);
  int*    work2  = (int*)alloc(G2SLOTS * 4);
  int*    rowTok = (int*)alloc(CAP_ROWS * 4);
  float*  rowW   = (float*)alloc(CAP_ROWS * 4);
  (void)ws_size; (void)in_sizes; (void)n_in; (void)out_size;

  // weight re-layout (padded)
  conv_gu_pad<<<2048, 256, 0, stream>>>((const float4*)SGU, (ushort4*)WguSP);
  conv_gu_pad<<<NEXP * 2048, 256, 0, stream>>>((const float4*)EGU, (ushort4*)WguEP);
  conv_dn_pad<<<4096, 256, 0, stream>>>(SD, WdSP);
  conv_dn_pad<<<NEXP * 4096, 256, 0, stream>>>(ED, WdEP);

  // routing
  init_kernel<<<(CAP_ROWS + 255) / 256, 256, 0, stream>>>(rowTok);
  router_kernel<<<TOKENS / 4, 256, 0, stream>>>(
      (const float4*)X, (const float4*)GW, Xb, e01, w01);
  hist_kernel<<<PLAN_BLOCKS, 256, 0, stream>>>(e01, blkCnt);
  plan_kernel<<<1, 256, 0, stream>>>(blkCnt, blkBas, tileEx, work1, work2);
  scatter_kernel<<<PLAN_BLOCKS, 256, 0, stream>>>(e01, w01, blkBas, rowTok, rowW);

  // GEMMs: R10 cores. gemm2_shared plain-writes all of Out (stream-ordered before
  // routed atomicAdds) -> no combine pass, no Yr buffer, idempotent on replay.
  gemm1_fused<<<G1SLOTS, 512, 0, stream>>>(
      Xb, WguSP, WguEP, As, Ar, rowTok, tileEx, work1);
  gemm2_shared<<<SH_TILES * 4, 512, 0, stream>>>(As, WdSP, Out);
  gemm2_routed<<<G2SLOTS, 512, 0, stream>>>(
      Ar, WdEP, Out, rowTok, rowW, tileEx, work2);
}